// Round 2
// baseline (1357.187 us; speedup 1.0000x reference)
//
#include <hip/hip_runtime.h>

#define NN 100000
#define NE 200000
#define MT (NN + NE)

__device__ __forceinline__ float bf2f(unsigned short u) {
    union { unsigned int i; float f; } v; v.i = ((unsigned int)u) << 16; return v.f;
}
__device__ __forceinline__ unsigned short f2bf(float f) {
    union { unsigned int i; float f; } v; v.f = f;
    unsigned int r = v.i + 0x7fffu + ((v.i >> 16) & 1u);
    return (unsigned short)(r >> 16);
}
__device__ __forceinline__ void unpack2(unsigned int u, float& lo, float& hi) {
    union { unsigned int i; float f; } a, b;
    a.i = u << 16; b.i = u & 0xffff0000u;
    lo = a.f; hi = b.f;
}
// Dtype-flexible scalar load: f32 flag ? read float : read bf16.
__device__ __forceinline__ float loadf(const void* p, size_t i, int f32) {
    return f32 ? ((const float*)p)[i] : bf2f(((const unsigned short*)p)[i]);
}

// Detect input dtype: for bf16 data, low ushort of each u32 word is a genuine
// N(0,1) value (sane exponent). For fp32 data it's random mantissa bits
// (~89% insane exponents). flag=1 => inputs are fp32.
__global__ void detect_kernel(const unsigned int* __restrict__ x, int* flag) {
    __shared__ int cnt;
    if (threadIdx.x == 0) cnt = 0;
    __syncthreads();
    int bad = 0;
    for (int i = threadIdx.x; i < 1024; i += 256) {
        unsigned int e = (x[i] >> 7) & 0xFF;
        if (e == 0xFF || (e > 0 && (e < 107 || e > 134))) bad++;
    }
    atomicAdd(&cnt, bad);
    __syncthreads();
    if (threadIdx.x == 0) *flag = (cnt > 256) ? 1 : 0;
}

// Build combined weight mats (f32) and summed biases.
// Wx cols: [theta_x | theta_deg | theta_r0 | theta_r1 | gamma_x]
// Wy cols: [gamma_y | gamma_deg | gamma_r0 | gamma_r1 | theta_y]
__global__ __launch_bounds__(256) void prep_kernel(
    const void* txw, const void* tdw, const void* tyw,
    const void* gyw, const void* gdw, const void* gxw,
    const void* trw, const void* grw,
    const void* txb, const void* tdb, const void* tyb,
    const void* gyb, const void* gdb, const void* gxb,
    const void* trb, const void* grb,
    float* Wx, float* Wy, float* bx, float* by, const int* flagp)
{
    int f32 = *flagp;
    int t = blockIdx.x * 256 + threadIdx.x;
    if (t < 5120) {
        int j = t / 160, fo = t - j * 160, m = fo >> 5, f = fo & 31;
        size_t idx = (size_t)j * 32 + f;
        float vx, vy;
        if (m == 0)      { vx = loadf(txw, idx, f32);        vy = loadf(gyw, idx, f32); }
        else if (m == 1) { vx = loadf(tdw, idx, f32);        vy = loadf(gdw, idx, f32); }
        else if (m == 2) { vx = loadf(trw, idx, f32);        vy = loadf(grw, idx, f32); }
        else if (m == 3) { vx = loadf(trw, 1024 + idx, f32); vy = loadf(grw, 1024 + idx, f32); }
        else             { vx = loadf(gxw, idx, f32);        vy = loadf(tyw, idx, f32); }
        Wx[t] = vx; Wy[t] = vy;
    } else if (t < 5152) {
        int f = t - 5120;
        bx[f] = loadf(txb, f, f32) + loadf(tdb, f, f32) + loadf(tyb, f, f32)
              + loadf(trb, f, f32) + loadf(trb, 32 + f, f32);
        by[f] = loadf(gyb, f, f32) + loadf(gdb, f, f32) + loadf(gxb, f, f32)
              + loadf(grb, f, f32) + loadf(grb, 32 + f, f32);
    }
}

// H[row, 0:160] = feat[row, 0:32] @ Wcat  (bf16 out). For y-rows, cols 128:160
// (= y @ theta_y_w) are also atomically scattered into xacc[dst[row]] (segment_sum).
__global__ __launch_bounds__(256) void gemm_h(
    const void* __restrict__ x, const void* __restrict__ y,
    const float* __restrict__ Wx, const float* __restrict__ Wy,
    const int* __restrict__ dst,
    unsigned short* __restrict__ Xh, unsigned short* __restrict__ Yh,
    float* __restrict__ xacc, const int* __restrict__ flagp)
{
    int f32 = *flagp;
    int tid = blockIdx.x * 256 + threadIdx.x;   // MT*40 threads, 4 outputs each
    int row = tid / 40;
    int q = tid - row * 40;
    if (row >= MT) return;
    const void* feat; const float* W; unsigned short* H; int r; bool is_y;
    if (row < NN) { feat = x; W = Wx; H = Xh; r = row; is_y = false; }
    else          { feat = y; W = Wy; H = Yh; r = row - NN; is_y = true; }

    float v[32];
    if (f32) {
        const float4* fp = (const float4*)((const float*)feat + (size_t)r * 32);
#pragma unroll
        for (int i = 0; i < 8; ++i) {
            float4 A = fp[i];
            v[4*i] = A.x; v[4*i+1] = A.y; v[4*i+2] = A.z; v[4*i+3] = A.w;
        }
    } else {
        const uint4* fp = (const uint4*)((const unsigned short*)feat + (size_t)r * 32);
#pragma unroll
        for (int i = 0; i < 4; ++i) {
            uint4 A = fp[i];
            unpack2(A.x, v[8*i],   v[8*i+1]); unpack2(A.y, v[8*i+2], v[8*i+3]);
            unpack2(A.z, v[8*i+4], v[8*i+5]); unpack2(A.w, v[8*i+6], v[8*i+7]);
        }
    }

    float a0 = 0.f, a1 = 0.f, a2 = 0.f, a3 = 0.f;
    const float* Wc = W + q * 4;
#pragma unroll
    for (int j = 0; j < 32; ++j) {
        float4 w = *(const float4*)(Wc + j * 160);
        a0 = fmaf(v[j], w.x, a0); a1 = fmaf(v[j], w.y, a1);
        a2 = fmaf(v[j], w.z, a2); a3 = fmaf(v[j], w.w, a3);
    }
    ushort4 o; o.x = f2bf(a0); o.y = f2bf(a1); o.z = f2bf(a2); o.w = f2bf(a3);
    *(ushort4*)(H + (size_t)r * 160 + q * 4) = o;

    if (is_y && q >= 32) {
        int d = dst[r];
        float* p = xacc + (size_t)d * 32 + (q - 32) * 4;
        atomicAdd(p + 0, a0); atomicAdd(p + 1, a1);
        atomicAdd(p + 2, a2); atomicAdd(p + 3, a3);
    }
}

// Per-row: self + deg*self_deg + sum_t(H[.,64:96]) + sum_tt(H[.,96:128]) + acc/aux + bias,
// relu on upper half, store pre-BN (f32 or bf16), accumulate per-feature sum/sumsq.
__global__ __launch_bounds__(256) void gather_kernel(
    const unsigned short* __restrict__ H,     // this side's [M,160]
    const unsigned short* __restrict__ Haux,  // other side's H (aux gather) or null
    const float* __restrict__ acc_in,         // xacc (x side) or null
    const int* __restrict__ aux_idx,          // pm_pd (y side) or null
    const void* __restrict__ deg,             // [M]
    const int* __restrict__ t, const int* __restrict__ tt,   // [M,16]
    const float* __restrict__ bias,           // [32]
    float* __restrict__ pre_f,                // [M,32] f32 out (x side; aliases acc_in)
    unsigned short* __restrict__ pre_h,       // [M,32] bf16 out (y side)
    float* __restrict__ ssum, float* __restrict__ ssq,       // [32]
    int M, const int* __restrict__ flagp)
{
    __shared__ int s_idx[8][32];
    __shared__ float s_deg[8];
    __shared__ float s_sum[32];
    __shared__ float s_sq[32];
    int f32 = *flagp;
    int l = threadIdx.x >> 5, f = threadIdx.x & 31;
    if (threadIdx.x < 32) { s_sum[f] = 0.f; s_sq[f] = 0.f; }
    int row = blockIdx.x * 8 + l;
    bool act = row < M;
    int r = act ? row : 0;
    if (f < 16) s_idx[l][f] = t[r * 16 + f];
    else        s_idx[l][f] = tt[r * 16 + (f - 16)];
    if (f == 0) s_deg[l] = loadf(deg, r, f32);
    __syncthreads();

    const unsigned short* Hr = H + (size_t)r * 160;
    float a = bias[f];
    a += bf2f(Hr[f]);
    a += s_deg[l] * bf2f(Hr[32 + f]);
#pragma unroll
    for (int k = 0; k < 16; ++k)
        a += bf2f(H[(size_t)s_idx[l][k] * 160 + 64 + f]);
#pragma unroll
    for (int k = 0; k < 16; ++k)
        a += bf2f(H[(size_t)s_idx[l][16 + k] * 160 + 96 + f]);
    if (acc_in)  a += acc_in[(size_t)r * 32 + f];
    if (aux_idx) a += bf2f(Haux[(size_t)aux_idx[r] * 160 + 128 + f]);
    if (f >= 16) a = fmaxf(a, 0.f);
    if (act) {
        if (pre_f) pre_f[(size_t)r * 32 + f] = a;
        else       pre_h[(size_t)r * 32 + f] = f2bf(a);
    }

    float av = act ? a : 0.f;
    atomicAdd(&s_sum[f], av);
    atomicAdd(&s_sq[f], av * av);
    __syncthreads();
    if (threadIdx.x < 32) {
        atomicAdd(&ssum[f], s_sum[f]);
        atomicAdd(&ssq[f], s_sq[f]);
    }
}

__global__ void finalize_stats(
    const float* ssx, const float* sqx, const float* ssy, const float* sqy,
    const void* bnxw, const void* bnxb, const void* bnyw, const void* bnyb,
    float* scsh, const int* flagp)   // [scale_x|shift_x|scale_y|shift_y], 32 each
{
    int f32 = *flagp;
    int f = threadIdx.x;
    if (f < 32) {
        float m = ssx[f] / (float)NN;
        float var = sqx[f] / (float)NN - m * m;
        float inv = rsqrtf(var + 1e-5f);
        float sc = loadf(bnxw, f, f32) * inv;
        scsh[f] = sc; scsh[32 + f] = loadf(bnxb, f, f32) - m * sc;
    } else if (f < 64) {
        int g = f - 32;
        float m = ssy[g] / (float)NE;
        float var = sqy[g] / (float)NE - m * m;
        float inv = rsqrtf(var + 1e-5f);
        float sc = loadf(bnyw, g, f32) * inv;
        scsh[64 + g] = sc; scsh[96 + g] = loadf(bnyb, g, f32) - m * sc;
    }
}

__global__ __launch_bounds__(256) void apply_bn(
    const float* __restrict__ xpre, const unsigned short* __restrict__ ypre,
    const float* __restrict__ scsh, void* __restrict__ out,
    const int* __restrict__ flagp)
{
    int f32 = *flagp;
    int tid = blockIdx.x * 256 + threadIdx.x;   // MT*8 threads, 4 elems each
    if (tid >= MT * 8) return;
    int fq = (tid & 7) * 4;
    const float* sc;
    float4 v;
    if (tid < NN * 8) {
        v = ((const float4*)xpre)[tid];
        sc = scsh;
    } else {
        size_t off = (size_t)tid * 4 - (size_t)NN * 32;
        ushort4 u = *(const ushort4*)(ypre + off);
        v.x = bf2f(u.x); v.y = bf2f(u.y); v.z = bf2f(u.z); v.w = bf2f(u.w);
        sc = scsh + 64;
    }
    float o0 = v.x * sc[fq + 0] + sc[32 + fq + 0];
    float o1 = v.y * sc[fq + 1] + sc[32 + fq + 1];
    float o2 = v.z * sc[fq + 2] + sc[32 + fq + 2];
    float o3 = v.w * sc[fq + 3] + sc[32 + fq + 3];
    if (f32) {
        float4 o; o.x = o0; o.y = o1; o.z = o2; o.w = o3;
        ((float4*)out)[tid] = o;
    } else {
        ushort4 o; o.x = f2bf(o0); o.y = f2bf(o1); o.z = f2bf(o2); o.w = f2bf(o3);
        ((ushort4*)out)[tid] = o;
    }
}

extern "C" void kernel_launch(void* const* d_in, const int* in_sizes, int n_in,
                              void* d_out, int out_size, void* d_ws, size_t ws_size,
                              hipStream_t stream)
{
    const void* x      = d_in[0];
    const void* y      = d_in[1];
    const void* deg_g  = d_in[2];
    const void* deg_lg = d_in[3];
    const int* t_g   = (const int*)d_in[4];
    const int* tt_g  = (const int*)d_in[5];
    const int* t_lg  = (const int*)d_in[6];
    const int* tt_lg = (const int*)d_in[7];
    const int* dst   = (const int*)d_in[8];
    const int* pm_pd = (const int*)d_in[9];

    char* ws = (char*)d_ws;
    int*   flag  = (int*)ws;                    // 4 B
    float* Wx    = (float*)(ws + 256);          // 5120 f32
    float* Wy    = Wx + 5120;                   // 5120
    float* bx    = Wy + 5120;                   // 32
    float* by    = bx + 32;                     // 32
    float* stats = by + 32;                     // 128 (sum_x, sq_x, sum_y, sq_y)
    float* scsh  = stats + 128;                 // 128
    unsigned short* Xh = (unsigned short*)(ws + 65536);   // NN*160 bf16 = 32 MB
    unsigned short* Yh = Xh + (size_t)NN * 160;           // NE*160 bf16 = 64 MB
    float* xacc = (float*)(Yh + (size_t)NE * 160);        // NN*32 f32 (doubles as xpre)
    unsigned short* ypre = (unsigned short*)(xacc + (size_t)NN * 32);  // NE*32 bf16
    // total ws use: 65536 + 32e6 + 64e6 + 12.8e6 + 12.8e6 = 121.67 MB

    hipMemsetAsync(stats, 0, 256 * sizeof(float), stream);
    hipMemsetAsync(xacc, 0, (size_t)NN * 32 * sizeof(float), stream);

    detect_kernel<<<1, 256, 0, stream>>>((const unsigned int*)x, flag);
    prep_kernel<<<21, 256, 0, stream>>>(d_in[10], d_in[12], d_in[14], d_in[16],
                                        d_in[18], d_in[20], d_in[22], d_in[24],
                                        d_in[11], d_in[13], d_in[15], d_in[17],
                                        d_in[19], d_in[21], d_in[23], d_in[25],
                                        Wx, Wy, bx, by, flag);
    gemm_h<<<46875, 256, 0, stream>>>(x, y, Wx, Wy, dst, Xh, Yh, xacc, flag);
    gather_kernel<<<12500, 256, 0, stream>>>(Xh, nullptr, xacc, nullptr, deg_g,
                                             t_g, tt_g, bx, xacc, nullptr,
                                             stats + 0, stats + 32, NN, flag);
    gather_kernel<<<25000, 256, 0, stream>>>(Yh, Xh, nullptr, pm_pd, deg_lg,
                                             t_lg, tt_lg, by, nullptr, ypre,
                                             stats + 64, stats + 96, NE, flag);
    finalize_stats<<<1, 64, 0, stream>>>(stats + 0, stats + 32, stats + 64, stats + 96,
                                         d_in[26], d_in[27], d_in[28], d_in[29],
                                         scsh, flag);
    apply_bn<<<9375, 256, 0, stream>>>(xacc, ypre, scsh, d_out, flag);
}

// Round 3
// 1330.773 us; speedup vs baseline: 1.0198x; 1.0198x over previous
//
#include <hip/hip_runtime.h>

#define NN 100000
#define NE 200000
#define MT (NN + NE)

__device__ __forceinline__ float bf2f(unsigned short u) {
    union { unsigned int i; float f; } v; v.i = ((unsigned int)u) << 16; return v.f;
}
__device__ __forceinline__ unsigned short f2bf(float f) {
    union { unsigned int i; float f; } v; v.f = f;
    unsigned int r = v.i + 0x7fffu + ((v.i >> 16) & 1u);
    return (unsigned short)(r >> 16);
}
__device__ __forceinline__ void unpack2(unsigned int u, float& lo, float& hi) {
    union { unsigned int i; float f; } a, b;
    a.i = u << 16; b.i = u & 0xffff0000u;
    lo = a.f; hi = b.f;
}
__device__ __forceinline__ unsigned int pack2(float a, float b) {
    return (unsigned int)f2bf(a) | ((unsigned int)f2bf(b) << 16);
}
__device__ __forceinline__ float loadf(const void* p, size_t i, int f32) {
    return f32 ? ((const float*)p)[i] : bf2f(((const unsigned short*)p)[i]);
}

// Detect input dtype (bf16 vs f32) from bit patterns of x. flag=1 => fp32.
__global__ void detect_kernel(const unsigned int* __restrict__ x, int* flag) {
    __shared__ int cnt;
    if (threadIdx.x == 0) cnt = 0;
    __syncthreads();
    int bad = 0;
    for (int i = threadIdx.x; i < 1024; i += 256) {
        unsigned int e = (x[i] >> 7) & 0xFF;
        if (e == 0xFF || (e > 0 && (e < 107 || e > 134))) bad++;
    }
    atomicAdd(&cnt, bad);
    __syncthreads();
    if (threadIdx.x == 0) *flag = (cnt > 256) ? 1 : 0;
}

// Combined weights, layout W[m][j][f] = W[m*1024 + j*32 + f], f32.
// Wx m: [theta_x | theta_deg | theta_r0 | theta_r1 | gamma_x]
// Wy m: [gamma_y | gamma_deg | gamma_r0 | gamma_r1 | theta_y]
__global__ __launch_bounds__(256) void prep_kernel(
    const void* txw, const void* tdw, const void* tyw,
    const void* gyw, const void* gdw, const void* gxw,
    const void* trw, const void* grw,
    const void* txb, const void* tdb, const void* tyb,
    const void* gyb, const void* gdb, const void* gxb,
    const void* trb, const void* grb,
    float* Wx, float* Wy, float* bx, float* by, const int* flagp)
{
    int f32 = *flagp;
    int t = blockIdx.x * 256 + threadIdx.x;
    if (t < 5120) {
        int m = t >> 10, rem = t & 1023;
        size_t idx = rem;
        float vx, vy;
        if (m == 0)      { vx = loadf(txw, idx, f32);        vy = loadf(gyw, idx, f32); }
        else if (m == 1) { vx = loadf(tdw, idx, f32);        vy = loadf(gdw, idx, f32); }
        else if (m == 2) { vx = loadf(trw, idx, f32);        vy = loadf(grw, idx, f32); }
        else if (m == 3) { vx = loadf(trw, 1024 + idx, f32); vy = loadf(grw, 1024 + idx, f32); }
        else             { vx = loadf(gxw, idx, f32);        vy = loadf(tyw, idx, f32); }
        Wx[t] = vx; Wy[t] = vy;
    } else if (t < 5152) {
        int f = t - 5120;
        bx[f] = loadf(txb, f, f32) + loadf(tdb, f, f32) + loadf(tyb, f, f32)
              + loadf(trb, f, f32) + loadf(trb, 32 + f, f32);
        by[f] = loadf(gyb, f, f32) + loadf(gdb, f, f32) + loadf(gxb, f, f32)
              + loadf(grb, f, f32) + loadf(grb, 32 + f, f32);
    }
}

// Per row r: Self[r] = feat@W0 + deg[r]*(feat@W1) + bias  (bf16)
//            T[r]    = feat@W2,  TT[r] = feat@W3          (bf16)
//            x-side:  Aux[r] = feat@W4 (bf16)
//            y-side:  feat@W4 scattered into xacc[dst[r]] (f32 atomics)
// 8 threads per row, 4 features each, W staged in LDS. NN%32==0 so no
// block straddles the x/y boundary.
__global__ __launch_bounds__(256) void gemm_h(
    const void* __restrict__ x, const void* __restrict__ y,
    const float* __restrict__ Wx, const float* __restrict__ Wy,
    const float* __restrict__ bx, const float* __restrict__ by,
    const void* __restrict__ deg_g, const void* __restrict__ deg_lg,
    const int* __restrict__ dst,
    unsigned short* __restrict__ Xself, unsigned short* __restrict__ Xt,
    unsigned short* __restrict__ Xtt,   unsigned short* __restrict__ Xaux,
    unsigned short* __restrict__ Yself, unsigned short* __restrict__ Yt,
    unsigned short* __restrict__ Ytt,
    float* __restrict__ xacc, const int* __restrict__ flagp)
{
    __shared__ float sW[5120];
    int f32 = *flagp;
    int tid = blockIdx.x * 256 + threadIdx.x;
    int row = tid >> 3;
    int qf = tid & 7;                       // features 4*qf .. 4*qf+3
    bool is_y = (blockIdx.x >= 3125);       // NN*8/256 = 3125
    const float* Wg = is_y ? Wy : Wx;
    for (int i = threadIdx.x; i < 5120; i += 256) sW[i] = Wg[i];
    __syncthreads();
    if (row >= MT) return;
    int r = is_y ? row - NN : row;
    const void* feat = is_y ? y : x;

    float v[32];
    if (f32) {
        const float4* fp = (const float4*)((const float*)feat + (size_t)r * 32);
#pragma unroll
        for (int i = 0; i < 8; ++i) {
            float4 A = fp[i];
            v[4*i] = A.x; v[4*i+1] = A.y; v[4*i+2] = A.z; v[4*i+3] = A.w;
        }
    } else {
        const uint4* fp = (const uint4*)((const unsigned short*)feat + (size_t)r * 32);
#pragma unroll
        for (int i = 0; i < 4; ++i) {
            uint4 A = fp[i];
            unpack2(A.x, v[8*i],   v[8*i+1]); unpack2(A.y, v[8*i+2], v[8*i+3]);
            unpack2(A.z, v[8*i+4], v[8*i+5]); unpack2(A.w, v[8*i+6], v[8*i+7]);
        }
    }

    float acc[5][4];
#pragma unroll
    for (int m = 0; m < 5; ++m)
#pragma unroll
        for (int i = 0; i < 4; ++i) acc[m][i] = 0.f;

    const float* wp = sW + qf * 4;
#pragma unroll
    for (int j = 0; j < 32; ++j) {
#pragma unroll
        for (int m = 0; m < 5; ++m) {
            float4 w = *(const float4*)(wp + m * 1024 + j * 32);
            acc[m][0] = fmaf(v[j], w.x, acc[m][0]);
            acc[m][1] = fmaf(v[j], w.y, acc[m][1]);
            acc[m][2] = fmaf(v[j], w.z, acc[m][2]);
            acc[m][3] = fmaf(v[j], w.w, acc[m][3]);
        }
    }

    size_t o = (size_t)r * 32 + qf * 4;
    float dg = loadf(is_y ? deg_lg : deg_g, r, f32);
    const float* bias = is_y ? by : bx;
    float s0 = acc[0][0] + dg * acc[1][0] + bias[qf*4+0];
    float s1 = acc[0][1] + dg * acc[1][1] + bias[qf*4+1];
    float s2 = acc[0][2] + dg * acc[1][2] + bias[qf*4+2];
    float s3 = acc[0][3] + dg * acc[1][3] + bias[qf*4+3];
    ushort4 us; us.x = f2bf(s0); us.y = f2bf(s1); us.z = f2bf(s2); us.w = f2bf(s3);
    ushort4 ut; ut.x = f2bf(acc[2][0]); ut.y = f2bf(acc[2][1]);
    ut.z = f2bf(acc[2][2]); ut.w = f2bf(acc[2][3]);
    ushort4 uu; uu.x = f2bf(acc[3][0]); uu.y = f2bf(acc[3][1]);
    uu.z = f2bf(acc[3][2]); uu.w = f2bf(acc[3][3]);
    if (!is_y) {
        *(ushort4*)(Xself + o) = us;
        *(ushort4*)(Xt + o)    = ut;
        *(ushort4*)(Xtt + o)   = uu;
        ushort4 ua; ua.x = f2bf(acc[4][0]); ua.y = f2bf(acc[4][1]);
        ua.z = f2bf(acc[4][2]); ua.w = f2bf(acc[4][3]);
        *(ushort4*)(Xaux + o)  = ua;
    } else {
        *(ushort4*)(Yself + o) = us;
        *(ushort4*)(Yt + o)    = ut;
        *(ushort4*)(Ytt + o)   = uu;
        int d = dst[r];
        float* p = xacc + (size_t)d * 32 + qf * 4;
        atomicAdd(p + 0, acc[4][0]); atomicAdd(p + 1, acc[4][1]);
        atomicAdd(p + 2, acc[4][2]); atomicAdd(p + 3, acc[4][3]);
    }
}

// Thread per (row, quarter): 8 features, 16-B gathers from compact [M,32] arrays.
// pre = Self[r] + sum_k T[t_k] + sum_k TT[tt_k] (+ accin[r] | Aux[aux_idx[r]]),
// relu upper half, store pre (f32 x-side / bf16 y-side), block-reduce BN stats.
__global__ __launch_bounds__(256) void gather_kernel(
    const unsigned short* __restrict__ Self,
    const unsigned short* __restrict__ T, const unsigned short* __restrict__ TT,
    const unsigned short* __restrict__ Aux,     // y-side, else null
    const float* __restrict__ accin,            // x-side (xacc), else null
    const int* __restrict__ t, const int* __restrict__ tt,   // [M,16]
    const int* __restrict__ aux_idx,            // y-side (pm_pd), else null
    float* __restrict__ pre_f,                  // x-side out (aliases accin)
    unsigned short* __restrict__ pre_h,         // y-side out
    float* __restrict__ ssum, float* __restrict__ ssq,
    int M)
{
    __shared__ int s_t[1024];
    __shared__ int s_tt[1024];
    __shared__ float s_sum[32];
    __shared__ float s_sq[32];
    if (threadIdx.x < 32) { s_sum[threadIdx.x] = 0.f; s_sq[threadIdx.x] = 0.f; }
    int row0 = blockIdx.x * 64;
    int lim = M * 16 - row0 * 16;
    for (int i = threadIdx.x; i < 1024; i += 256) {
        s_t[i]  = (i < lim) ? t[row0 * 16 + i]  : 0;
        s_tt[i] = (i < lim) ? tt[row0 * 16 + i] : 0;
    }
    __syncthreads();

    int lr = threadIdx.x >> 2, q = threadIdx.x & 3;   // 64 rows, 4 quarters
    int r = row0 + lr;
    bool act = r < M;
    int rc = act ? r : 0;

    float a[8];
    {
        uint4 u = *(const uint4*)(Self + (size_t)rc * 32 + q * 8);
        unpack2(u.x, a[0], a[1]); unpack2(u.y, a[2], a[3]);
        unpack2(u.z, a[4], a[5]); unpack2(u.w, a[6], a[7]);
    }
#pragma unroll
    for (int k = 0; k < 16; ++k) {
        int idx = s_t[lr * 16 + k];
        uint4 g = *(const uint4*)(T + (size_t)idx * 32 + q * 8);
        float e0, e1, e2, e3, e4, e5, e6, e7;
        unpack2(g.x, e0, e1); unpack2(g.y, e2, e3);
        unpack2(g.z, e4, e5); unpack2(g.w, e6, e7);
        a[0] += e0; a[1] += e1; a[2] += e2; a[3] += e3;
        a[4] += e4; a[5] += e5; a[6] += e6; a[7] += e7;
    }
#pragma unroll
    for (int k = 0; k < 16; ++k) {
        int idx = s_tt[lr * 16 + k];
        uint4 g = *(const uint4*)(TT + (size_t)idx * 32 + q * 8);
        float e0, e1, e2, e3, e4, e5, e6, e7;
        unpack2(g.x, e0, e1); unpack2(g.y, e2, e3);
        unpack2(g.z, e4, e5); unpack2(g.w, e6, e7);
        a[0] += e0; a[1] += e1; a[2] += e2; a[3] += e3;
        a[4] += e4; a[5] += e5; a[6] += e6; a[7] += e7;
    }
    if (accin) {
        float4 b0 = *(const float4*)(accin + (size_t)rc * 32 + q * 8);
        float4 b1 = *(const float4*)(accin + (size_t)rc * 32 + q * 8 + 4);
        a[0] += b0.x; a[1] += b0.y; a[2] += b0.z; a[3] += b0.w;
        a[4] += b1.x; a[5] += b1.y; a[6] += b1.z; a[7] += b1.w;
    }
    if (aux_idx) {
        int ai = aux_idx[rc];
        uint4 g = *(const uint4*)(Aux + (size_t)ai * 32 + q * 8);
        float e0, e1, e2, e3, e4, e5, e6, e7;
        unpack2(g.x, e0, e1); unpack2(g.y, e2, e3);
        unpack2(g.z, e4, e5); unpack2(g.w, e6, e7);
        a[0] += e0; a[1] += e1; a[2] += e2; a[3] += e3;
        a[4] += e4; a[5] += e5; a[6] += e6; a[7] += e7;
    }
    if (q >= 2) {   // features 16..31: relu
#pragma unroll
        for (int i = 0; i < 8; ++i) a[i] = fmaxf(a[i], 0.f);
    }
    if (act) {
        if (pre_f) {
            float4 o0, o1;
            o0.x = a[0]; o0.y = a[1]; o0.z = a[2]; o0.w = a[3];
            o1.x = a[4]; o1.y = a[5]; o1.z = a[6]; o1.w = a[7];
            *(float4*)(pre_f + (size_t)r * 32 + q * 8) = o0;
            *(float4*)(pre_f + (size_t)r * 32 + q * 8 + 4) = o1;
        } else {
            uint4 o;
            o.x = pack2(a[0], a[1]); o.y = pack2(a[2], a[3]);
            o.z = pack2(a[4], a[5]); o.w = pack2(a[6], a[7]);
            *(uint4*)(pre_h + (size_t)r * 32 + q * 8) = o;
        }
    } else {
#pragma unroll
        for (int i = 0; i < 8; ++i) a[i] = 0.f;
    }
#pragma unroll
    for (int i = 0; i < 8; ++i) {
        atomicAdd(&s_sum[q * 8 + i], a[i]);
        atomicAdd(&s_sq[q * 8 + i], a[i] * a[i]);
    }
    __syncthreads();
    if (threadIdx.x < 32) {
        atomicAdd(&ssum[threadIdx.x], s_sum[threadIdx.x]);
        atomicAdd(&ssq[threadIdx.x], s_sq[threadIdx.x]);
    }
}

__global__ void finalize_stats(
    const float* ssx, const float* sqx, const float* ssy, const float* sqy,
    const void* bnxw, const void* bnxb, const void* bnyw, const void* bnyb,
    float* scsh, const int* flagp)
{
    int f32 = *flagp;
    int f = threadIdx.x;
    if (f < 32) {
        float m = ssx[f] / (float)NN;
        float var = sqx[f] / (float)NN - m * m;
        float inv = rsqrtf(var + 1e-5f);
        float sc = loadf(bnxw, f, f32) * inv;
        scsh[f] = sc; scsh[32 + f] = loadf(bnxb, f, f32) - m * sc;
    } else if (f < 64) {
        int g = f - 32;
        float m = ssy[g] / (float)NE;
        float var = sqy[g] / (float)NE - m * m;
        float inv = rsqrtf(var + 1e-5f);
        float sc = loadf(bnyw, g, f32) * inv;
        scsh[64 + g] = sc; scsh[96 + g] = loadf(bnyb, g, f32) - m * sc;
    }
}

__global__ __launch_bounds__(256) void apply_bn(
    const float* __restrict__ xpre, const unsigned short* __restrict__ ypre,
    const float* __restrict__ scsh, void* __restrict__ out,
    const int* __restrict__ flagp)
{
    int f32 = *flagp;
    int tid = blockIdx.x * 256 + threadIdx.x;   // MT*8 threads, 4 elems each
    if (tid >= MT * 8) return;
    int fq = (tid & 7) * 4;
    const float* sc;
    float4 v;
    if (tid < NN * 8) {
        v = ((const float4*)xpre)[tid];
        sc = scsh;
    } else {
        size_t off = (size_t)tid * 4 - (size_t)NN * 32;
        ushort4 u = *(const ushort4*)(ypre + off);
        v.x = bf2f(u.x); v.y = bf2f(u.y); v.z = bf2f(u.z); v.w = bf2f(u.w);
        sc = scsh + 64;
    }
    float o0 = v.x * sc[fq + 0] + sc[32 + fq + 0];
    float o1 = v.y * sc[fq + 1] + sc[32 + fq + 1];
    float o2 = v.z * sc[fq + 2] + sc[32 + fq + 2];
    float o3 = v.w * sc[fq + 3] + sc[32 + fq + 3];
    if (f32) {
        float4 o; o.x = o0; o.y = o1; o.z = o2; o.w = o3;
        ((float4*)out)[tid] = o;
    } else {
        ushort4 o; o.x = f2bf(o0); o.y = f2bf(o1); o.z = f2bf(o2); o.w = f2bf(o3);
        ((ushort4*)out)[tid] = o;
    }
}

extern "C" void kernel_launch(void* const* d_in, const int* in_sizes, int n_in,
                              void* d_out, int out_size, void* d_ws, size_t ws_size,
                              hipStream_t stream)
{
    const void* x      = d_in[0];
    const void* y      = d_in[1];
    const void* deg_g  = d_in[2];
    const void* deg_lg = d_in[3];
    const int* t_g   = (const int*)d_in[4];
    const int* tt_g  = (const int*)d_in[5];
    const int* t_lg  = (const int*)d_in[6];
    const int* tt_lg = (const int*)d_in[7];
    const int* dst   = (const int*)d_in[8];
    const int* pm_pd = (const int*)d_in[9];

    char* ws = (char*)d_ws;
    int*   flag  = (int*)ws;                    // 4 B
    float* Wx    = (float*)(ws + 256);          // 5120 f32
    float* Wy    = Wx + 5120;
    float* bx    = Wy + 5120;
    float* by    = bx + 32;
    float* stats = by + 32;                     // 128
    float* scsh  = stats + 128;                 // 128
    unsigned short* Xself = (unsigned short*)(ws + 65536);    // N*32 bf16 = 6.4 MB
    unsigned short* Xt    = Xself + (size_t)NN * 32;
    unsigned short* Xtt   = Xt    + (size_t)NN * 32;
    unsigned short* Xaux  = Xtt   + (size_t)NN * 32;
    unsigned short* Yself = Xaux  + (size_t)NN * 32;          // E*32 bf16 = 12.8 MB
    unsigned short* Yt    = Yself + (size_t)NE * 32;
    unsigned short* Ytt   = Yt    + (size_t)NE * 32;
    float* xacc = (float*)(Ytt + (size_t)NE * 32);            // N*32 f32 (→ xpre)
    unsigned short* ypre = (unsigned short*)(xacc + (size_t)NN * 32);  // E*32 bf16
    // total ≈ 65536 + 25.6M + 38.4M + 12.8M + 12.8M ≈ 89.7 MB

    hipMemsetAsync(stats, 0, 256 * sizeof(float), stream);
    hipMemsetAsync(xacc, 0, (size_t)NN * 32 * sizeof(float), stream);

    detect_kernel<<<1, 256, 0, stream>>>((const unsigned int*)x, flag);
    prep_kernel<<<21, 256, 0, stream>>>(d_in[10], d_in[12], d_in[14], d_in[16],
                                        d_in[18], d_in[20], d_in[22], d_in[24],
                                        d_in[11], d_in[13], d_in[15], d_in[17],
                                        d_in[19], d_in[21], d_in[23], d_in[25],
                                        Wx, Wy, bx, by, flag);
    gemm_h<<<9375, 256, 0, stream>>>(x, y, Wx, Wy, bx, by, deg_g, deg_lg, dst,
                                     Xself, Xt, Xtt, Xaux, Yself, Yt, Ytt,
                                     xacc, flag);
    gather_kernel<<<1563, 256, 0, stream>>>(Xself, Xt, Xtt, nullptr, xacc,
                                            t_g, tt_g, nullptr,
                                            xacc, nullptr,
                                            stats + 0, stats + 32, NN);
    gather_kernel<<<3125, 256, 0, stream>>>(Yself, Yt, Ytt, Xaux, nullptr,
                                            t_lg, tt_lg, pm_pd,
                                            nullptr, ypre,
                                            stats + 64, stats + 96, NE);
    finalize_stats<<<1, 64, 0, stream>>>(stats + 0, stats + 32, stats + 64, stats + 96,
                                         d_in[26], d_in[27], d_in[28], d_in[29],
                                         scsh, flag);
    apply_bn<<<9375, 256, 0, stream>>>(xacc, ypre, scsh, d_out, flag);
}

// Round 4
// 488.411 us; speedup vs baseline: 2.7788x; 2.7247x over previous
//
#include <hip/hip_runtime.h>

#define NN 100000
#define NE 200000
#define MT (NN + NE)

__device__ __forceinline__ float bf2f(unsigned short u) {
    union { unsigned int i; float f; } v; v.i = ((unsigned int)u) << 16; return v.f;
}
__device__ __forceinline__ unsigned short f2bf(float f) {
    union { unsigned int i; float f; } v; v.f = f;
    unsigned int r = v.i + 0x7fffu + ((v.i >> 16) & 1u);
    return (unsigned short)(r >> 16);
}
__device__ __forceinline__ void unpack2(unsigned int u, float& lo, float& hi) {
    union { unsigned int i; float f; } a, b;
    a.i = u << 16; b.i = u & 0xffff0000u;
    lo = a.f; hi = b.f;
}
__device__ __forceinline__ unsigned int pack2(float a, float b) {
    return (unsigned int)f2bf(a) | ((unsigned int)f2bf(b) << 16);
}
__device__ __forceinline__ float loadf(const void* p, size_t i, int f32) {
    return f32 ? ((const float*)p)[i] : bf2f(((const unsigned short*)p)[i]);
}

// Detect input dtype (bf16 vs f32) from bit patterns of x. flag=1 => fp32.
__global__ void detect_kernel(const unsigned int* __restrict__ x, int* flag) {
    __shared__ int cnt;
    if (threadIdx.x == 0) cnt = 0;
    __syncthreads();
    int bad = 0;
    for (int i = threadIdx.x; i < 1024; i += 256) {
        unsigned int e = (x[i] >> 7) & 0xFF;
        if (e == 0xFF || (e > 0 && (e < 107 || e > 134))) bad++;
    }
    atomicAdd(&cnt, bad);
    __syncthreads();
    if (threadIdx.x == 0) *flag = (cnt > 256) ? 1 : 0;
}

// Combined weights, layout W[m][j][f] = W[m*1024 + j*32 + f], f32.
// Wx m: [theta_x | theta_deg | theta_r0 | theta_r1 | gamma_x]
// Wy m: [gamma_y | gamma_deg | gamma_r0 | gamma_r1 | theta_y]
__global__ __launch_bounds__(256) void prep_kernel(
    const void* txw, const void* tdw, const void* tyw,
    const void* gyw, const void* gdw, const void* gxw,
    const void* trw, const void* grw,
    const void* txb, const void* tdb, const void* tyb,
    const void* gyb, const void* gdb, const void* gxb,
    const void* trb, const void* grb,
    float* Wx, float* Wy, float* bx, float* by, const int* flagp)
{
    int f32 = *flagp;
    int t = blockIdx.x * 256 + threadIdx.x;
    if (t < 5120) {
        int m = t >> 10, rem = t & 1023;
        size_t idx = rem;
        float vx, vy;
        if (m == 0)      { vx = loadf(txw, idx, f32);        vy = loadf(gyw, idx, f32); }
        else if (m == 1) { vx = loadf(tdw, idx, f32);        vy = loadf(gdw, idx, f32); }
        else if (m == 2) { vx = loadf(trw, idx, f32);        vy = loadf(grw, idx, f32); }
        else if (m == 3) { vx = loadf(trw, 1024 + idx, f32); vy = loadf(grw, 1024 + idx, f32); }
        else             { vx = loadf(gxw, idx, f32);        vy = loadf(tyw, idx, f32); }
        Wx[t] = vx; Wy[t] = vy;
    } else if (t < 5152) {
        int f = t - 5120;
        bx[f] = loadf(txb, f, f32) + loadf(tdb, f, f32) + loadf(tyb, f, f32)
              + loadf(trb, f, f32) + loadf(trb, 32 + f, f32);
        by[f] = loadf(gyb, f, f32) + loadf(gdb, f, f32) + loadf(gxb, f, f32)
              + loadf(grb, f, f32) + loadf(grb, 32 + f, f32);
    }
}

// Per row r: Self[r] = feat@W0 + deg[r]*(feat@W1) + bias  (bf16)
//            T[r]    = feat@W2,  TT[r] = feat@W3          (bf16)
//            x-side:  Aux[r] = feat@W4 (bf16)
//            y-side:  feat@W4 scattered into xacc[dst[r]] (f32 atomics)
// 8 threads per row, 4 features each, W staged in LDS. NN%32==0 so no
// block straddles the x/y boundary.
// launch_bounds(256,4): cap 128 VGPR (R3 post-mortem: full unroll hit the
// 256-VGPR cap and spilled ~870 B/thread to scratch -> 3 GB HBM traffic).
// #pragma unroll 2 on the K loop keeps transient LDS-load registers ~40.
__global__ __launch_bounds__(256, 4) void gemm_h(
    const void* __restrict__ x, const void* __restrict__ y,
    const float* __restrict__ Wx, const float* __restrict__ Wy,
    const float* __restrict__ bx, const float* __restrict__ by,
    const void* __restrict__ deg_g, const void* __restrict__ deg_lg,
    const int* __restrict__ dst,
    unsigned short* __restrict__ Xself, unsigned short* __restrict__ Xt,
    unsigned short* __restrict__ Xtt,   unsigned short* __restrict__ Xaux,
    unsigned short* __restrict__ Yself, unsigned short* __restrict__ Yt,
    unsigned short* __restrict__ Ytt,
    float* __restrict__ xacc, const int* __restrict__ flagp)
{
    __shared__ float sW[5120];
    int f32 = *flagp;
    int tid = blockIdx.x * 256 + threadIdx.x;
    int row = tid >> 3;
    int qf = tid & 7;                       // features 4*qf .. 4*qf+3
    bool is_y = (blockIdx.x >= 3125);       // NN*8/256 = 3125
    const float* Wg = is_y ? Wy : Wx;
    for (int i = threadIdx.x; i < 5120; i += 256) sW[i] = Wg[i];
    __syncthreads();
    if (row >= MT) return;
    int r = is_y ? row - NN : row;
    const void* feat = is_y ? y : x;

    float v[32];
    if (f32) {
        const float4* fp = (const float4*)((const float*)feat + (size_t)r * 32);
#pragma unroll
        for (int i = 0; i < 8; ++i) {
            float4 A = fp[i];
            v[4*i] = A.x; v[4*i+1] = A.y; v[4*i+2] = A.z; v[4*i+3] = A.w;
        }
    } else {
        const uint4* fp = (const uint4*)((const unsigned short*)feat + (size_t)r * 32);
#pragma unroll
        for (int i = 0; i < 4; ++i) {
            uint4 A = fp[i];
            unpack2(A.x, v[8*i],   v[8*i+1]); unpack2(A.y, v[8*i+2], v[8*i+3]);
            unpack2(A.z, v[8*i+4], v[8*i+5]); unpack2(A.w, v[8*i+6], v[8*i+7]);
        }
    }

    float acc[5][4];
#pragma unroll
    for (int m = 0; m < 5; ++m)
#pragma unroll
        for (int i = 0; i < 4; ++i) acc[m][i] = 0.f;

    const float* wp = sW + qf * 4;
#pragma unroll 2
    for (int j = 0; j < 32; ++j) {
#pragma unroll
        for (int m = 0; m < 5; ++m) {
            float4 w = *(const float4*)(wp + m * 1024 + j * 32);
            acc[m][0] = fmaf(v[j], w.x, acc[m][0]);
            acc[m][1] = fmaf(v[j], w.y, acc[m][1]);
            acc[m][2] = fmaf(v[j], w.z, acc[m][2]);
            acc[m][3] = fmaf(v[j], w.w, acc[m][3]);
        }
    }

    size_t o = (size_t)r * 32 + qf * 4;
    float dg = loadf(is_y ? deg_lg : deg_g, r, f32);
    const float* bias = is_y ? by : bx;
    float s0 = acc[0][0] + dg * acc[1][0] + bias[qf*4+0];
    float s1 = acc[0][1] + dg * acc[1][1] + bias[qf*4+1];
    float s2 = acc[0][2] + dg * acc[1][2] + bias[qf*4+2];
    float s3 = acc[0][3] + dg * acc[1][3] + bias[qf*4+3];
    ushort4 us; us.x = f2bf(s0); us.y = f2bf(s1); us.z = f2bf(s2); us.w = f2bf(s3);
    ushort4 ut; ut.x = f2bf(acc[2][0]); ut.y = f2bf(acc[2][1]);
    ut.z = f2bf(acc[2][2]); ut.w = f2bf(acc[2][3]);
    ushort4 uu; uu.x = f2bf(acc[3][0]); uu.y = f2bf(acc[3][1]);
    uu.z = f2bf(acc[3][2]); uu.w = f2bf(acc[3][3]);
    if (!is_y) {
        *(ushort4*)(Xself + o) = us;
        *(ushort4*)(Xt + o)    = ut;
        *(ushort4*)(Xtt + o)   = uu;
        ushort4 ua; ua.x = f2bf(acc[4][0]); ua.y = f2bf(acc[4][1]);
        ua.z = f2bf(acc[4][2]); ua.w = f2bf(acc[4][3]);
        *(ushort4*)(Xaux + o)  = ua;
    } else {
        *(ushort4*)(Yself + o) = us;
        *(ushort4*)(Yt + o)    = ut;
        *(ushort4*)(Ytt + o)   = uu;
        int d = dst[r];
        float* p = xacc + (size_t)d * 32 + qf * 4;
        atomicAdd(p + 0, acc[4][0]); atomicAdd(p + 1, acc[4][1]);
        atomicAdd(p + 2, acc[4][2]); atomicAdd(p + 3, acc[4][3]);
    }
}

// Thread per (row, quarter): 8 features, 16-B gathers from compact [M,32] arrays.
// pre = Self[r] + sum_k T[t_k] + sum_k TT[tt_k] (+ accin[r] | Aux[aux_idx[r]]),
// relu upper half, store pre (f32 x-side / bf16 y-side), block-reduce BN stats.
__global__ __launch_bounds__(256) void gather_kernel(
    const unsigned short* __restrict__ Self,
    const unsigned short* __restrict__ T, const unsigned short* __restrict__ TT,
    const unsigned short* __restrict__ Aux,     // y-side, else null
    const float* __restrict__ accin,            // x-side (xacc), else null
    const int* __restrict__ t, const int* __restrict__ tt,   // [M,16]
    const int* __restrict__ aux_idx,            // y-side (pm_pd), else null
    float* __restrict__ pre_f,                  // x-side out (aliases accin)
    unsigned short* __restrict__ pre_h,         // y-side out
    float* __restrict__ ssum, float* __restrict__ ssq,
    int M)
{
    __shared__ int s_t[1024];
    __shared__ int s_tt[1024];
    __shared__ float s_sum[32];
    __shared__ float s_sq[32];
    if (threadIdx.x < 32) { s_sum[threadIdx.x] = 0.f; s_sq[threadIdx.x] = 0.f; }
    int row0 = blockIdx.x * 64;
    int lim = M * 16 - row0 * 16;
    for (int i = threadIdx.x; i < 1024; i += 256) {
        s_t[i]  = (i < lim) ? t[row0 * 16 + i]  : 0;
        s_tt[i] = (i < lim) ? tt[row0 * 16 + i] : 0;
    }
    __syncthreads();

    int lr = threadIdx.x >> 2, q = threadIdx.x & 3;   // 64 rows, 4 quarters
    int r = row0 + lr;
    bool act = r < M;
    int rc = act ? r : 0;

    float a[8];
    {
        uint4 u = *(const uint4*)(Self + (size_t)rc * 32 + q * 8);
        unpack2(u.x, a[0], a[1]); unpack2(u.y, a[2], a[3]);
        unpack2(u.z, a[4], a[5]); unpack2(u.w, a[6], a[7]);
    }
#pragma unroll
    for (int k = 0; k < 16; ++k) {
        int idx = s_t[lr * 16 + k];
        uint4 g = *(const uint4*)(T + (size_t)idx * 32 + q * 8);
        float e0, e1, e2, e3, e4, e5, e6, e7;
        unpack2(g.x, e0, e1); unpack2(g.y, e2, e3);
        unpack2(g.z, e4, e5); unpack2(g.w, e6, e7);
        a[0] += e0; a[1] += e1; a[2] += e2; a[3] += e3;
        a[4] += e4; a[5] += e5; a[6] += e6; a[7] += e7;
    }
#pragma unroll
    for (int k = 0; k < 16; ++k) {
        int idx = s_tt[lr * 16 + k];
        uint4 g = *(const uint4*)(TT + (size_t)idx * 32 + q * 8);
        float e0, e1, e2, e3, e4, e5, e6, e7;
        unpack2(g.x, e0, e1); unpack2(g.y, e2, e3);
        unpack2(g.z, e4, e5); unpack2(g.w, e6, e7);
        a[0] += e0; a[1] += e1; a[2] += e2; a[3] += e3;
        a[4] += e4; a[5] += e5; a[6] += e6; a[7] += e7;
    }
    if (accin) {
        float4 b0 = *(const float4*)(accin + (size_t)rc * 32 + q * 8);
        float4 b1 = *(const float4*)(accin + (size_t)rc * 32 + q * 8 + 4);
        a[0] += b0.x; a[1] += b0.y; a[2] += b0.z; a[3] += b0.w;
        a[4] += b1.x; a[5] += b1.y; a[6] += b1.z; a[7] += b1.w;
    }
    if (aux_idx) {
        int ai = aux_idx[rc];
        uint4 g = *(const uint4*)(Aux + (size_t)ai * 32 + q * 8);
        float e0, e1, e2, e3, e4, e5, e6, e7;
        unpack2(g.x, e0, e1); unpack2(g.y, e2, e3);
        unpack2(g.z, e4, e5); unpack2(g.w, e6, e7);
        a[0] += e0; a[1] += e1; a[2] += e2; a[3] += e3;
        a[4] += e4; a[5] += e5; a[6] += e6; a[7] += e7;
    }
    if (q >= 2) {   // features 16..31: relu
#pragma unroll
        for (int i = 0; i < 8; ++i) a[i] = fmaxf(a[i], 0.f);
    }
    if (act) {
        if (pre_f) {
            float4 o0, o1;
            o0.x = a[0]; o0.y = a[1]; o0.z = a[2]; o0.w = a[3];
            o1.x = a[4]; o1.y = a[5]; o1.z = a[6]; o1.w = a[7];
            *(float4*)(pre_f + (size_t)r * 32 + q * 8) = o0;
            *(float4*)(pre_f + (size_t)r * 32 + q * 8 + 4) = o1;
        } else {
            uint4 o;
            o.x = pack2(a[0], a[1]); o.y = pack2(a[2], a[3]);
            o.z = pack2(a[4], a[5]); o.w = pack2(a[6], a[7]);
            *(uint4*)(pre_h + (size_t)r * 32 + q * 8) = o;
        }
    } else {
#pragma unroll
        for (int i = 0; i < 8; ++i) a[i] = 0.f;
    }
#pragma unroll
    for (int i = 0; i < 8; ++i) {
        atomicAdd(&s_sum[q * 8 + i], a[i]);
        atomicAdd(&s_sq[q * 8 + i], a[i] * a[i]);
    }
    __syncthreads();
    if (threadIdx.x < 32) {
        atomicAdd(&ssum[threadIdx.x], s_sum[threadIdx.x]);
        atomicAdd(&ssq[threadIdx.x], s_sq[threadIdx.x]);
    }
}

__global__ void finalize_stats(
    const float* ssx, const float* sqx, const float* ssy, const float* sqy,
    const void* bnxw, const void* bnxb, const void* bnyw, const void* bnyb,
    float* scsh, const int* flagp)
{
    int f32 = *flagp;
    int f = threadIdx.x;
    if (f < 32) {
        float m = ssx[f] / (float)NN;
        float var = sqx[f] / (float)NN - m * m;
        float inv = rsqrtf(var + 1e-5f);
        float sc = loadf(bnxw, f, f32) * inv;
        scsh[f] = sc; scsh[32 + f] = loadf(bnxb, f, f32) - m * sc;
    } else if (f < 64) {
        int g = f - 32;
        float m = ssy[g] / (float)NE;
        float var = sqy[g] / (float)NE - m * m;
        float inv = rsqrtf(var + 1e-5f);
        float sc = loadf(bnyw, g, f32) * inv;
        scsh[64 + g] = sc; scsh[96 + g] = loadf(bnyb, g, f32) - m * sc;
    }
}

__global__ __launch_bounds__(256) void apply_bn(
    const float* __restrict__ xpre, const unsigned short* __restrict__ ypre,
    const float* __restrict__ scsh, void* __restrict__ out,
    const int* __restrict__ flagp)
{
    int f32 = *flagp;
    int tid = blockIdx.x * 256 + threadIdx.x;   // MT*8 threads, 4 elems each
    if (tid >= MT * 8) return;
    int fq = (tid & 7) * 4;
    const float* sc;
    float4 v;
    if (tid < NN * 8) {
        v = ((const float4*)xpre)[tid];
        sc = scsh;
    } else {
        size_t off = (size_t)tid * 4 - (size_t)NN * 32;
        ushort4 u = *(const ushort4*)(ypre + off);
        v.x = bf2f(u.x); v.y = bf2f(u.y); v.z = bf2f(u.z); v.w = bf2f(u.w);
        sc = scsh + 64;
    }
    float o0 = v.x * sc[fq + 0] + sc[32 + fq + 0];
    float o1 = v.y * sc[fq + 1] + sc[32 + fq + 1];
    float o2 = v.z * sc[fq + 2] + sc[32 + fq + 2];
    float o3 = v.w * sc[fq + 3] + sc[32 + fq + 3];
    if (f32) {
        float4 o; o.x = o0; o.y = o1; o.z = o2; o.w = o3;
        ((float4*)out)[tid] = o;
    } else {
        ushort4 o; o.x = f2bf(o0); o.y = f2bf(o1); o.z = f2bf(o2); o.w = f2bf(o3);
        ((ushort4*)out)[tid] = o;
    }
}

extern "C" void kernel_launch(void* const* d_in, const int* in_sizes, int n_in,
                              void* d_out, int out_size, void* d_ws, size_t ws_size,
                              hipStream_t stream)
{
    const void* x      = d_in[0];
    const void* y      = d_in[1];
    const void* deg_g  = d_in[2];
    const void* deg_lg = d_in[3];
    const int* t_g   = (const int*)d_in[4];
    const int* tt_g  = (const int*)d_in[5];
    const int* t_lg  = (const int*)d_in[6];
    const int* tt_lg = (const int*)d_in[7];
    const int* dst   = (const int*)d_in[8];
    const int* pm_pd = (const int*)d_in[9];

    char* ws = (char*)d_ws;
    int*   flag  = (int*)ws;                    // 4 B
    float* Wx    = (float*)(ws + 256);          // 5120 f32
    float* Wy    = Wx + 5120;
    float* bx    = Wy + 5120;
    float* by    = bx + 32;
    float* stats = by + 32;                     // 128
    float* scsh  = stats + 128;                 // 128
    unsigned short* Xself = (unsigned short*)(ws + 65536);    // N*32 bf16 = 6.4 MB
    unsigned short* Xt    = Xself + (size_t)NN * 32;
    unsigned short* Xtt   = Xt    + (size_t)NN * 32;
    unsigned short* Xaux  = Xtt   + (size_t)NN * 32;
    unsigned short* Yself = Xaux  + (size_t)NN * 32;          // E*32 bf16 = 12.8 MB
    unsigned short* Yt    = Yself + (size_t)NE * 32;
    unsigned short* Ytt   = Yt    + (size_t)NE * 32;
    float* xacc = (float*)(Ytt + (size_t)NE * 32);            // N*32 f32 (→ xpre)
    unsigned short* ypre = (unsigned short*)(xacc + (size_t)NN * 32);  // E*32 bf16
    // total ≈ 65536 + 25.6M + 38.4M + 12.8M + 12.8M ≈ 89.7 MB

    hipMemsetAsync(stats, 0, 256 * sizeof(float), stream);
    hipMemsetAsync(xacc, 0, (size_t)NN * 32 * sizeof(float), stream);

    detect_kernel<<<1, 256, 0, stream>>>((const unsigned int*)x, flag);
    prep_kernel<<<21, 256, 0, stream>>>(d_in[10], d_in[12], d_in[14], d_in[16],
                                        d_in[18], d_in[20], d_in[22], d_in[24],
                                        d_in[11], d_in[13], d_in[15], d_in[17],
                                        d_in[19], d_in[21], d_in[23], d_in[25],
                                        Wx, Wy, bx, by, flag);
    gemm_h<<<9375, 256, 0, stream>>>(x, y, Wx, Wy, bx, by, deg_g, deg_lg, dst,
                                     Xself, Xt, Xtt, Xaux, Yself, Yt, Ytt,
                                     xacc, flag);
    gather_kernel<<<1563, 256, 0, stream>>>(Xself, Xt, Xtt, nullptr, xacc,
                                            t_g, tt_g, nullptr,
                                            xacc, nullptr,
                                            stats + 0, stats + 32, NN);
    gather_kernel<<<3125, 256, 0, stream>>>(Yself, Yt, Ytt, Xaux, nullptr,
                                            t_lg, tt_lg, pm_pd,
                                            nullptr, ypre,
                                            stats + 64, stats + 96, NE);
    finalize_stats<<<1, 64, 0, stream>>>(stats + 0, stats + 32, stats + 64, stats + 96,
                                         d_in[26], d_in[27], d_in[28], d_in[29],
                                         scsh, flag);
    apply_bn<<<9375, 256, 0, stream>>>(xacc, ypre, scsh, d_out, flag);
}

// Round 7
// 424.170 us; speedup vs baseline: 3.1996x; 1.1515x over previous
//
#include <hip/hip_runtime.h>

#define NN 100000
#define NE 200000
#define MT (NN + NE)

typedef unsigned short u16;
typedef __attribute__((ext_vector_type(8))) short bf16x8;
typedef __attribute__((ext_vector_type(4))) float f32x4;

__device__ __forceinline__ float bf2f(u16 u) {
    union { unsigned int i; float f; } v; v.i = ((unsigned int)u) << 16; return v.f;
}
__device__ __forceinline__ u16 f2bf(float f) {
    union { unsigned int i; float f; } v; v.f = f;
    unsigned int r = v.i + 0x7fffu + ((v.i >> 16) & 1u);
    return (u16)(r >> 16);
}
__device__ __forceinline__ void unpack2(unsigned int u, float& lo, float& hi) {
    union { unsigned int i; float f; } a, b;
    a.i = u << 16; b.i = u & 0xffff0000u;
    lo = a.f; hi = b.f;
}
__device__ __forceinline__ unsigned int pack2(float a, float b) {
    return (unsigned int)f2bf(a) | ((unsigned int)f2bf(b) << 16);
}
// Dtype-flexible scalar load (R2-R4 proven): f32 flag ? float : bf16.
__device__ __forceinline__ float loadf(const void* p, size_t i, int f32) {
    return f32 ? ((const float*)p)[i] : bf2f(((const u16*)p)[i]);
}

// Detect input dtype from bit patterns of x (R2-R4 proven). flag=1 => fp32.
// Evidence across rounds says this fires flag=1: R1/R5/R6 (hardcoded bf16)
// all NaN'd; R2-R4 (flag-adaptive) all passed.
__global__ void detect_kernel(const unsigned int* __restrict__ x, int* flag) {
    __shared__ int cnt;
    if (threadIdx.x == 0) cnt = 0;
    __syncthreads();
    int bad = 0;
    for (int i = threadIdx.x; i < 1024; i += 256) {
        unsigned int e = (x[i] >> 7) & 0xFF;
        if (e == 0xFF || (e > 0 && (e < 107 || e > 134))) bad++;
    }
    atomicAdd(&cnt, bad);
    __syncthreads();
    if (threadIdx.x == 0) *flag = (cnt > 256) ? 1 : 0;
}

// Build MFMA B-operand fragments (bf16) and summed f32 biases.
// Bf[b*512 + lane*8 + j] = W_m[k][f], m=b>>1, k=(lane>>4)*8+j,
// f=(b&1)*16+(lane&15)  — the 16x16x32 B-operand layout.
// x side m: [theta_x | theta_deg | theta_r0 | theta_r1 | gamma_x]
// y side m: [gamma_y | gamma_deg | gamma_r0 | gamma_r1 | theta_y]
__global__ __launch_bounds__(256) void prep_kernel(
    const void* txw, const void* tdw, const void* tyw,
    const void* gyw, const void* gdw, const void* gxw,
    const void* trw, const void* grw,
    const void* txb, const void* tdb, const void* tyb,
    const void* gyb, const void* gdb, const void* gxb,
    const void* trb, const void* grb,
    u16* Bfx, u16* Bfy, float* bx, float* by, const int* flagp)
{
    int f32 = *flagp;
    int t = blockIdx.x * 256 + threadIdx.x;
    if (t < 10240) {
        int side = t / 5120;
        int e = t - side * 5120;
        int b = e >> 9, lane = (e >> 3) & 63, j = e & 7;
        int m = b >> 1;
        int k = ((lane >> 4) << 3) + j;
        int f = ((b & 1) << 4) + (lane & 15);
        size_t idx = (size_t)k * 32 + f;
        float v;
        if (side == 0) {
            v = (m == 0) ? loadf(txw, idx, f32) : (m == 1) ? loadf(tdw, idx, f32)
              : (m == 2) ? loadf(trw, idx, f32) : (m == 3) ? loadf(trw, 1024 + idx, f32)
              : loadf(gxw, idx, f32);
            Bfx[e] = f2bf(v);
        } else {
            v = (m == 0) ? loadf(gyw, idx, f32) : (m == 1) ? loadf(gdw, idx, f32)
              : (m == 2) ? loadf(grw, idx, f32) : (m == 3) ? loadf(grw, 1024 + idx, f32)
              : loadf(tyw, idx, f32);
            Bfy[e] = f2bf(v);
        }
    } else if (t < 10304) {
        int f = t - 10240;
        if (f < 32) {
            bx[f] = loadf(txb, f, f32) + loadf(tdb, f, f32) + loadf(tyb, f, f32)
                  + loadf(trb, f, f32) + loadf(trb, 32 + f, f32);
        } else {
            f -= 32;
            by[f] = loadf(gyb, f, f32) + loadf(gdb, f, f32) + loadf(gxb, f, f32)
                  + loadf(grb, f, f32) + loadf(grb, 32 + f, f32);
        }
    }
}

// MFMA GEMM: per wave, 16 rows x 160 cols in 10 mfma_f32_16x16x32_bf16.
// Direct global u16 stores from the D-fragment (quad's 16 lanes cover 32
// consecutive bytes per row — coalescer merges).
__global__ __launch_bounds__(256, 4) void gemm2(
    const void* __restrict__ x, const void* __restrict__ y,
    const u16* __restrict__ Bfx, const u16* __restrict__ Bfy,
    const float* __restrict__ bx, const float* __restrict__ by,
    const void* __restrict__ deg_g, const void* __restrict__ deg_lg,
    const int* __restrict__ dst,
    u16* __restrict__ Xself, u16* __restrict__ Xt,
    u16* __restrict__ Xtt,   u16* __restrict__ Xaux,
    u16* __restrict__ Yself, u16* __restrict__ Yt, u16* __restrict__ Ytt,
    float* __restrict__ xacc, const int* __restrict__ flagp)
{
    int f32 = *flagp;
    int lane = threadIdx.x & 63;
    int wib  = threadIdx.x >> 6;
    bool is_y = (blockIdx.x >= 1563);                 // x: 1563 blocks, y: 3125
    int wid = (is_y ? (int)blockIdx.x - 1563 : (int)blockIdx.x) * 4 + wib;
    int nwaves = is_y ? 12500 : 6250;                 // 200000/16, 100000/16
    if (wid >= nwaves) return;
    int r0 = wid * 16;

    const void* feat = is_y ? y : x;
    const u16* Bf   = is_y ? Bfy : Bfx;
    const float* bias = is_y ? by : bx;
    const void* deg  = is_y ? deg_lg : deg_g;

    // A fragment: lane holds A[m=lane&15][k=(lane>>4)*8 + j].
    union { u16 s[8]; bf16x8 v; } au;
    {
        size_t eoff = (size_t)(r0 + (lane & 15)) * 32 + ((lane >> 4) << 3);
        if (f32) {
            const float4* fp = (const float4*)((const float*)feat + eoff);
            float4 A0 = fp[0], A1 = fp[1];
            au.s[0] = f2bf(A0.x); au.s[1] = f2bf(A0.y);
            au.s[2] = f2bf(A0.z); au.s[3] = f2bf(A0.w);
            au.s[4] = f2bf(A1.x); au.s[5] = f2bf(A1.y);
            au.s[6] = f2bf(A1.z); au.s[7] = f2bf(A1.w);
        } else {
            au.v = *(const bf16x8*)((const u16*)feat + eoff);
        }
    }
    f32x4 acc[10];
    const u16* bp = Bf + lane * 8;
#pragma unroll
    for (int b = 0; b < 10; ++b) {
        bf16x8 bfr = *(const bf16x8*)(bp + b * 512);
        f32x4 z = {0.f, 0.f, 0.f, 0.f};
        acc[b] = __builtin_amdgcn_mfma_f32_16x16x32_bf16(au.v, bfr, z, 0, 0, 0);
    }

    // D layout: col = lane&15, row = (lane>>4)*4 + i
    int n = lane & 15, quad = lane >> 4;
    int rowb = r0 + quad * 4;
    float bl = bias[n], bh = bias[16 + n];

#pragma unroll
    for (int i = 0; i < 4; ++i) {
        float dgi = loadf(deg, rowb + i, f32);
        size_t ro = (size_t)(rowb + i) * 32;
        u16 s_lo = f2bf(acc[0][i] + dgi * acc[2][i] + bl);
        u16 s_hi = f2bf(acc[1][i] + dgi * acc[3][i] + bh);
        if (!is_y) {
            Xself[ro + n]      = s_lo;
            Xself[ro + 16 + n] = s_hi;
            Xt[ro + n]         = f2bf(acc[4][i]);
            Xt[ro + 16 + n]    = f2bf(acc[5][i]);
            Xtt[ro + n]        = f2bf(acc[6][i]);
            Xtt[ro + 16 + n]   = f2bf(acc[7][i]);
            Xaux[ro + n]       = f2bf(acc[8][i]);
            Xaux[ro + 16 + n]  = f2bf(acc[9][i]);
        } else {
            Yself[ro + n]      = s_lo;
            Yself[ro + 16 + n] = s_hi;
            Yt[ro + n]         = f2bf(acc[4][i]);
            Yt[ro + 16 + n]    = f2bf(acc[5][i]);
            Ytt[ro + n]        = f2bf(acc[6][i]);
            Ytt[ro + 16 + n]   = f2bf(acc[7][i]);
            int d = dst[rowb + i];
            float* p = xacc + (size_t)d * 32;
            atomicAdd(p + n,      acc[8][i]);
            atomicAdd(p + 16 + n, acc[9][i]);
        }
    }
}

// Fused x+y gather. Thread per (row, quarter): 8 features via 16-B gathers.
// Explicit 8-deep load staging for memory-level parallelism.
__global__ __launch_bounds__(256) void gather_fused(
    const u16* __restrict__ Xself, const u16* __restrict__ Xt,
    const u16* __restrict__ Xtt,   const u16* __restrict__ Xaux,
    const u16* __restrict__ Yself, const u16* __restrict__ Yt,
    const u16* __restrict__ Ytt,
    const float* __restrict__ xacc,
    const int* __restrict__ t_g, const int* __restrict__ tt_g,
    const int* __restrict__ t_lg, const int* __restrict__ tt_lg,
    const int* __restrict__ pm_pd,
    float* __restrict__ xpre, u16* __restrict__ ypre,
    float* __restrict__ stats)   // [sx(32)|qx(32)|sy(32)|qy(32)]
{
    __shared__ int s_t[1024];
    __shared__ int s_tt[1024];
    __shared__ float s_sum[32];
    __shared__ float s_sq[32];
    bool is_y = (blockIdx.x >= 1563);
    int M = is_y ? NE : NN;
    const u16 *Self, *T, *TT;
    const int *tl, *ttl;
    if (is_y) { Self = Yself; T = Yt; TT = Ytt; tl = t_lg; ttl = tt_lg; }
    else      { Self = Xself; T = Xt; TT = Xtt; tl = t_g;  ttl = tt_g; }
    float* ss = stats + (is_y ? 64 : 0);

    if (threadIdx.x < 32) { s_sum[threadIdx.x] = 0.f; s_sq[threadIdx.x] = 0.f; }
    int row0 = (is_y ? (int)blockIdx.x - 1563 : (int)blockIdx.x) * 64;
    int lim = (M - row0) * 16;
    for (int i = threadIdx.x; i < 1024; i += 256) {
        s_t[i]  = (i < lim) ? tl[row0 * 16 + i]  : 0;
        s_tt[i] = (i < lim) ? ttl[row0 * 16 + i] : 0;
    }
    __syncthreads();

    int lr = threadIdx.x >> 2, q = threadIdx.x & 3;
    int r = row0 + lr;
    bool act = r < M;
    int rc = act ? r : row0;

    float a[8];
    {
        uint4 u = *(const uint4*)(Self + (size_t)rc * 32 + q * 8);
        unpack2(u.x, a[0], a[1]); unpack2(u.y, a[2], a[3]);
        unpack2(u.z, a[4], a[5]); unpack2(u.w, a[6], a[7]);
    }
    const int* il = &s_t[lr * 16];
    const int* ill = &s_tt[lr * 16];
#pragma unroll
    for (int batch = 0; batch < 2; ++batch) {
        uint4 g[8];
#pragma unroll
        for (int j = 0; j < 8; ++j)
            g[j] = *(const uint4*)(T + (size_t)il[batch * 8 + j] * 32 + q * 8);
#pragma unroll
        for (int j = 0; j < 8; ++j) {
            float e0, e1, e2, e3, e4, e5, e6, e7;
            unpack2(g[j].x, e0, e1); unpack2(g[j].y, e2, e3);
            unpack2(g[j].z, e4, e5); unpack2(g[j].w, e6, e7);
            a[0] += e0; a[1] += e1; a[2] += e2; a[3] += e3;
            a[4] += e4; a[5] += e5; a[6] += e6; a[7] += e7;
        }
    }
#pragma unroll
    for (int batch = 0; batch < 2; ++batch) {
        uint4 g[8];
#pragma unroll
        for (int j = 0; j < 8; ++j)
            g[j] = *(const uint4*)(TT + (size_t)ill[batch * 8 + j] * 32 + q * 8);
#pragma unroll
        for (int j = 0; j < 8; ++j) {
            float e0, e1, e2, e3, e4, e5, e6, e7;
            unpack2(g[j].x, e0, e1); unpack2(g[j].y, e2, e3);
            unpack2(g[j].z, e4, e5); unpack2(g[j].w, e6, e7);
            a[0] += e0; a[1] += e1; a[2] += e2; a[3] += e3;
            a[4] += e4; a[5] += e5; a[6] += e6; a[7] += e7;
        }
    }
    if (!is_y) {
        float4 b0 = *(const float4*)(xacc + (size_t)rc * 32 + q * 8);
        float4 b1 = *(const float4*)(xacc + (size_t)rc * 32 + q * 8 + 4);
        a[0] += b0.x; a[1] += b0.y; a[2] += b0.z; a[3] += b0.w;
        a[4] += b1.x; a[5] += b1.y; a[6] += b1.z; a[7] += b1.w;
    } else {
        int ai = pm_pd[rc];
        uint4 g = *(const uint4*)(Xaux + (size_t)ai * 32 + q * 8);
        float e0, e1, e2, e3, e4, e5, e6, e7;
        unpack2(g.x, e0, e1); unpack2(g.y, e2, e3);
        unpack2(g.z, e4, e5); unpack2(g.w, e6, e7);
        a[0] += e0; a[1] += e1; a[2] += e2; a[3] += e3;
        a[4] += e4; a[5] += e5; a[6] += e6; a[7] += e7;
    }
    if (q >= 2) {
#pragma unroll
        for (int i = 0; i < 8; ++i) a[i] = fmaxf(a[i], 0.f);
    }
    if (act) {
        if (!is_y) {
            float4 o0, o1;
            o0.x = a[0]; o0.y = a[1]; o0.z = a[2]; o0.w = a[3];
            o1.x = a[4]; o1.y = a[5]; o1.z = a[6]; o1.w = a[7];
            *(float4*)(xpre + (size_t)r * 32 + q * 8) = o0;
            *(float4*)(xpre + (size_t)r * 32 + q * 8 + 4) = o1;
        } else {
            uint4 o;
            o.x = pack2(a[0], a[1]); o.y = pack2(a[2], a[3]);
            o.z = pack2(a[4], a[5]); o.w = pack2(a[6], a[7]);
            *(uint4*)(ypre + (size_t)r * 32 + q * 8) = o;
        }
    } else {
#pragma unroll
        for (int i = 0; i < 8; ++i) a[i] = 0.f;
    }
#pragma unroll
    for (int i = 0; i < 8; ++i) {
        atomicAdd(&s_sum[q * 8 + i], a[i]);
        atomicAdd(&s_sq[q * 8 + i], a[i] * a[i]);
    }
    __syncthreads();
    if (threadIdx.x < 32) {
        atomicAdd(&ss[threadIdx.x], s_sum[threadIdx.x]);
        atomicAdd(&ss[32 + threadIdx.x], s_sq[threadIdx.x]);
    }
}

__global__ void finalize_stats(
    const float* stats,
    const void* bnxw, const void* bnxb, const void* bnyw, const void* bnyb,
    float* scsh, const int* flagp)
{
    int f32 = *flagp;
    int f = threadIdx.x;
    if (f < 32) {
        float m = stats[f] / (float)NN;
        float var = stats[32 + f] / (float)NN - m * m;
        float inv = rsqrtf(var + 1e-5f);
        float sc = loadf(bnxw, f, f32) * inv;
        scsh[f] = sc; scsh[32 + f] = loadf(bnxb, f, f32) - m * sc;
    } else if (f < 64) {
        int g = f - 32;
        float m = stats[64 + g] / (float)NE;
        float var = stats[96 + g] / (float)NE - m * m;
        float inv = rsqrtf(var + 1e-5f);
        float sc = loadf(bnyw, g, f32) * inv;
        scsh[64 + g] = sc; scsh[96 + g] = loadf(bnyb, g, f32) - m * sc;
    }
}

__global__ __launch_bounds__(256) void apply_bn(
    const float* __restrict__ xpre, const u16* __restrict__ ypre,
    const float* __restrict__ scsh, void* __restrict__ out,
    const int* __restrict__ flagp)
{
    int f32 = *flagp;
    int tid = blockIdx.x * 256 + threadIdx.x;   // MT*8 threads, 4 elems each
    if (tid >= MT * 8) return;
    int fq = (tid & 7) * 4;
    const float* sc;
    float4 v;
    if (tid < NN * 8) {
        v = ((const float4*)xpre)[tid];
        sc = scsh;
    } else {
        size_t off = (size_t)tid * 4 - (size_t)NN * 32;
        ushort4 u = *(const ushort4*)(ypre + off);
        v.x = bf2f(u.x); v.y = bf2f(u.y); v.z = bf2f(u.z); v.w = bf2f(u.w);
        sc = scsh + 64;
    }
    float o0 = v.x * sc[fq + 0] + sc[32 + fq + 0];
    float o1 = v.y * sc[fq + 1] + sc[32 + fq + 1];
    float o2 = v.z * sc[fq + 2] + sc[32 + fq + 2];
    float o3 = v.w * sc[fq + 3] + sc[32 + fq + 3];
    if (f32) {
        float4 o; o.x = o0; o.y = o1; o.z = o2; o.w = o3;
        ((float4*)out)[tid] = o;
    } else {
        ushort4 o; o.x = f2bf(o0); o.y = f2bf(o1); o.z = f2bf(o2); o.w = f2bf(o3);
        ((ushort4*)out)[tid] = o;
    }
}

extern "C" void kernel_launch(void* const* d_in, const int* in_sizes, int n_in,
                              void* d_out, int out_size, void* d_ws, size_t ws_size,
                              hipStream_t stream)
{
    const void* x      = d_in[0];
    const void* y      = d_in[1];
    const void* deg_g  = d_in[2];
    const void* deg_lg = d_in[3];
    const int* t_g   = (const int*)d_in[4];
    const int* tt_g  = (const int*)d_in[5];
    const int* t_lg  = (const int*)d_in[6];
    const int* tt_lg = (const int*)d_in[7];
    const int* dst   = (const int*)d_in[8];
    const int* pm_pd = (const int*)d_in[9];

    char* ws = (char*)d_ws;
    int*   flag = (int*)ws;                     // 4 B
    u16* Bfx   = (u16*)(ws + 256);              // 5120 u16 = 10 KB
    u16* Bfy   = Bfx + 5120;                    // 10 KB
    float* bx  = (float*)(ws + 24576);          // 32 f32
    float* by  = bx + 32;
    float* stats = by + 32;                     // 128 f32
    float* scsh  = stats + 128;                 // 128 f32
    u16* Xself = (u16*)(ws + 65536);            // NN*32 = 6.4 MB each
    u16* Xt    = Xself + (size_t)NN * 32;
    u16* Xtt   = Xt    + (size_t)NN * 32;
    u16* Xaux  = Xtt   + (size_t)NN * 32;
    u16* Yself = Xaux  + (size_t)NN * 32;       // NE*32 = 12.8 MB each
    u16* Yt    = Yself + (size_t)NE * 32;
    u16* Ytt   = Yt    + (size_t)NE * 32;
    float* xacc = (float*)(Ytt + (size_t)NE * 32);   // NN*32 f32 (→ xpre)
    u16* ypre = (u16*)(xacc + (size_t)NN * 32);      // NE*32 bf16
    // total ≈ 64 KB + 25.6 + 38.4 + 12.8 + 12.8 MB ≈ 89.7 MB

    hipMemsetAsync(stats, 0, 256 * sizeof(float), stream);
    hipMemsetAsync(xacc, 0, (size_t)NN * 32 * sizeof(float), stream);

    detect_kernel<<<1, 256, 0, stream>>>((const unsigned int*)x, flag);
    prep_kernel<<<41, 256, 0, stream>>>(
        d_in[10], d_in[12], d_in[14], d_in[16], d_in[18], d_in[20],
        d_in[22], d_in[24],
        d_in[11], d_in[13], d_in[15], d_in[17], d_in[19], d_in[21],
        d_in[23], d_in[25],
        Bfx, Bfy, bx, by, flag);
    gemm2<<<4688, 256, 0, stream>>>(x, y, Bfx, Bfy, bx, by, deg_g, deg_lg, dst,
                                    Xself, Xt, Xtt, Xaux, Yself, Yt, Ytt,
                                    xacc, flag);
    gather_fused<<<4688, 256, 0, stream>>>(Xself, Xt, Xtt, Xaux, Yself, Yt, Ytt,
                                           xacc, t_g, tt_g, t_lg, tt_lg, pm_pd,
                                           xacc, ypre, stats);
    finalize_stats<<<1, 64, 0, stream>>>(stats, d_in[26], d_in[27], d_in[28],
                                         d_in[29], scsh, flag);
    apply_bn<<<9375, 256, 0, stream>>>(xacc, ypre, scsh, d_out, flag);
}